// Round 3
// baseline (37553.384 us; speedup 1.0000x reference)
//
#include <hip/hip_runtime.h>
#include <hip/hip_bf16.h>
#include <math.h>

#define T_STEPS 2048
#define N_MOD   64
#define N_HID   256
#define N_INP   128

// Relaxed agent-scope atomics (sc1 -> LLC, coherent across XCDs)
#define AG_LD(p)        __hip_atomic_load((p),  __ATOMIC_RELAXED, __HIP_MEMORY_SCOPE_AGENT)
#define AG_ST(p, v)     __hip_atomic_store((p), (v), __ATOMIC_RELAXED, __HIP_MEMORY_SCOPE_AGENT)
#define AG_ST_REL(p, v) __hip_atomic_store((p), (v), __ATOMIC_RELEASE, __HIP_MEMORY_SCOPE_AGENT)

// --------------------------------------------------------------------------
// Pre-pass: xpre[t,n,h] = sum_i x2h[n,h,i] * x[t,i]  -> fb_seq region of d_out.
// Stepping kernel reads xpre[t] (one step ahead) then overwrites with fb[t].
// --------------------------------------------------------------------------
__global__ __launch_bounds__(256, 2) void xpre_kernel(
    const float* __restrict__ x, const float* __restrict__ x2h,
    float* __restrict__ out)
{
  __shared__ float xl[64 * N_INP];
  const int tb = blockIdx.x;
  const int n  = blockIdx.y;
  const int t  = threadIdx.x;

  const float4* xs  = (const float4*)(x + (size_t)tb * 64 * N_INP);
  float4*       xld = (float4*)xl;
  for (int k = t; k < 64 * N_INP / 4; k += 256) xld[k] = xs[k];

  float w[N_INP];
  const float* wrow = x2h + ((size_t)n * N_HID + t) * N_INP;
#pragma unroll
  for (int j = 0; j < N_INP; j += 4) {
    const float4 a = *(const float4*)(wrow + j);
    w[j] = a.x; w[j+1] = a.y; w[j+2] = a.z; w[j+3] = a.w;
  }
  __syncthreads();

  for (int tt = 0; tt < 64; ++tt) {
    float a0=0.f, a1=0.f, a2=0.f, a3=0.f;
#pragma unroll
    for (int j = 0; j < N_INP; j += 4) {
      const float4 h4 = *(const float4*)&xl[tt * N_INP + j];
      a0 = fmaf(w[j],   h4.x, a0);
      a1 = fmaf(w[j+1], h4.y, a1);
      a2 = fmaf(w[j+2], h4.z, a2);
      a3 = fmaf(w[j+3], h4.w, a3);
    }
    out[((size_t)(tb*64 + tt) * N_MOD + n) * N_HID + t] = (a0+a1)+(a2+a3);
  }
}

// --------------------------------------------------------------------------
// Persistent stepping kernel: 64 WGs x 512 threads, one WG per module.
// Thread t: h = t&255, half c = t>>8.
//
// u-formulation: fb[m] = wm @ u[m],  u[m] = sum_m' conn[m,m'] * hy[m'].
// -> publish RAW hy right after the update (nothing heavy before the flag);
//    the wm matvec runs post-gather from VGPR-resident wv[128].
//
// Iteration k (steady state):
//  A: update from {xpre_k, r_k, fb_k} -> hy_{k+1}, hz_{k+1}; hy -> LDS
//  B: publish hy_{k+1} -> hyb[(k+1)&1]; barrier; t0: flag = k+1 (release)
//  C: r_{k+1} = h2h . hy_{k+1}  (256KB L2 stream, OVERLAPS flag propagation);
//     write out_states[k+1], out_fb[k]; prefetch xpre_{k+1}
//  D: poll 64 flags >= k+1; barrier; acquire fence;
//     redu: u-partials (32 modules per half); barrier;
//     fb_{k+1} = wv . u (VGPR matvec, LDS-broadcast u); barrier
//
// Buffer safety: overwriting hyb[(k+1)&1] at iter k is safe because poll(k)
// at iter k-1 proved every WG finished iter k-2's gather of that parity.
// amdgpu_waves_per_eu(2,2): VGPR budget 256 so wv[128] stays resident.
// --------------------------------------------------------------------------
__global__ __attribute__((amdgpu_flat_work_group_size(512, 512),
                          amdgpu_waves_per_eu(2, 2)))
void archnet_step(
    const float* __restrict__ init, const float* __restrict__ wm,
    const float* __restrict__ conn, const float* __restrict__ h2h,
    const float* __restrict__ bias,
    float* __restrict__ out_states, float* __restrict__ out_fb,
    float* hyb, unsigned* flags)
{
  const int m = blockIdx.x;         // 0..63
  const int t = threadIdx.x;        // 0..511
  const int h = t & 255;
  const int c = t >> 8;             // 0 or 1

  __shared__ float hy[N_HID];
  __shared__ float redr[512];
  __shared__ float redu[512];
  __shared__ float redf[512];
  __shared__ float connrow[N_MOD];

  // ---- resident feedback weights: wm[h, c*128 .. +128) ----
  float wv[128];
  {
    const float* wp = wm + (size_t)h * N_HID + c * 128;
#pragma unroll
    for (int j = 0; j < 128; j += 4) {
      const float4 a = *(const float4*)(wp + j);
      wv[j] = a.x; wv[j+1] = a.y; wv[j+2] = a.z; wv[j+3] = a.w;
    }
  }

  // ---- init ----
  float biasv = 0.f, hzv = 0.f, xq = 0.f, hyn = 0.f, hzn = 0.f, fbv = 0.f;
  if (t < N_HID) {
    const float hy0 = init[(size_t)m * 512 + t];
    hy[t] = hy0;
    biasv = bias[(size_t)m * N_HID + h];
    hzv   = init[(size_t)m * 512 + 256 + h];
    out_states[(size_t)m * 512 + h]       = hy0;
    out_states[(size_t)m * 512 + 256 + h] = hzv;
    xq = out_fb[(size_t)m * N_HID + h];                 // xpre_0
  }
  if (t < N_MOD) connrow[t] = conn[m * N_MOD + t];
  redf[t] = 0.f;                                        // fb_0 = 0
  __syncthreads();

  const float* whbase = h2h + ((size_t)m * N_HID + h) * N_HID + c * 128;
  const float* hyc    = &hy[c * 128];

  // ---- pre-loop: r_0 ----
  {
    float b0=0.f, b1=0.f, b2=0.f, b3=0.f;
#pragma unroll
    for (int j = 0; j < 128; j += 4) {
      const float4 a  = *(const float4*)(whbase + j);
      const float4 h4 = *(const float4*)(hyc + j);
      b0 = fmaf(a.x, h4.x, b0);
      b1 = fmaf(a.y, h4.y, b1);
      b2 = fmaf(a.z, h4.z, b2);
      b3 = fmaf(a.w, h4.w, b3);
    }
    redr[t] = (b0+b1)+(b2+b3);
  }
  __syncthreads();

  for (int k = 0; k < T_STEPS; ++k) {
    // ---- A: update ----
    if (t < N_HID) {
      fbv = redf[h] + redf[h + 256];
      const float r   = redr[h] + redr[h + 256];
      const float pre = xq + r + biasv + fbv;
      const float th  = tanhf(pre);
      const float hyo = hy[h];
      hzn = hzv + 0.01f * (th - hyo - hzv);   // GAMMA=EPS=1, DT=0.01
      hyn = hyo + 0.01f * hzn;
      hzv = hzn;
      hy[h] = hyn;
    }

    // ---- B: publish + flag (nothing heavy before this point) ----
    float* hb = hyb + (size_t)((k + 1) & 1) * (N_MOD * N_HID);
    if (t < N_HID) AG_ST(&hb[m * N_HID + h], hyn);
    __syncthreads();                       // drains publishes; hy LDS visible
    if (t == 0) AG_ST_REL(&flags[m * 4], (unsigned)(k + 1));

    // ---- C: window work (overlaps flag propagation everywhere) ----
    {
      float b0=0.f, b1=0.f, b2=0.f, b3=0.f;
#pragma unroll
      for (int j = 0; j < 128; j += 4) {
        const float4 a  = *(const float4*)(whbase + j);
        const float4 h4 = *(const float4*)(hyc + j);
        b0 = fmaf(a.x, h4.x, b0);
        b1 = fmaf(a.y, h4.y, b1);
        b2 = fmaf(a.z, h4.z, b2);
        b3 = fmaf(a.w, h4.w, b3);
      }
      redr[t] = (b0+b1)+(b2+b3);           // r_{k+1}
    }
    if (t < N_HID) {
      const size_t ob = ((size_t)(k + 1) * N_MOD + m) * 512;
      out_states[ob + h]       = hyn;
      out_states[ob + 256 + h] = hzn;
      out_fb[((size_t)k * N_MOD + m) * N_HID + h] = fbv;
      if (k + 1 < T_STEPS)
        xq = out_fb[((size_t)(k + 1) * N_MOD + m) * N_HID + h];
    }

    // ---- D: poll + gather + resident matvec ----
    if (k + 1 < T_STEPS) {
      if (t < N_MOD) {
        while (AG_LD(&flags[t * 4]) < (unsigned)(k + 1)) { }
      }
      __syncthreads();
      __builtin_amdgcn_fence(__ATOMIC_ACQUIRE, "agent");
      {
        // u-partial over module group c: redu[t] = sum conn[m,mm]*hy[mm,h]
        float g0=0.f, g1=0.f, g2=0.f, g3=0.f;
#pragma unroll
        for (int mp = 0; mp < 32; mp += 4) {
          const int mm = c * 32 + mp;
          g0 = fmaf(connrow[mm+0], AG_LD(&hb[(size_t)(mm+0) * N_HID + h]), g0);
          g1 = fmaf(connrow[mm+1], AG_LD(&hb[(size_t)(mm+1) * N_HID + h]), g1);
          g2 = fmaf(connrow[mm+2], AG_LD(&hb[(size_t)(mm+2) * N_HID + h]), g2);
          g3 = fmaf(connrow[mm+3], AG_LD(&hb[(size_t)(mm+3) * N_HID + h]), g3);
        }
        redu[t] = (g0+g1)+(g2+g3);
      }
      __syncthreads();
      {
        // fb-partial: sum_j wv[j] * u[c*128+j],  u[j]=redu[j]+redu[j+256]
        float f0=0.f, f1=0.f, f2=0.f, f3=0.f;
#pragma unroll
        for (int jj = 0; jj < 128; jj += 4) {
          const int u0 = c * 128 + jj;
          f0 = fmaf(wv[jj],   redu[u0]   + redu[u0+256],   f0);
          f1 = fmaf(wv[jj+1], redu[u0+1] + redu[u0+1+256], f1);
          f2 = fmaf(wv[jj+2], redu[u0+2] + redu[u0+2+256], f2);
          f3 = fmaf(wv[jj+3], redu[u0+3] + redu[u0+3+256], f3);
        }
        redf[t] = (f0+f1)+(f2+f3);
      }
      __syncthreads();
    }
  }
}

// --------------------------------------------------------------------------
extern "C" void kernel_launch(void* const* d_in, const int* in_sizes, int n_in,
                              void* d_out, int out_size, void* d_ws, size_t ws_size,
                              hipStream_t stream) {
  const float* x    = (const float*)d_in[0];   // (2048,128)
  const float* init = (const float*)d_in[1];   // (64,2,256)
  const float* wmw  = (const float*)d_in[2];   // (256,256)
  const float* conn = (const float*)d_in[3];   // (64,64)
  const float* x2h  = (const float*)d_in[4];   // (64,256,128)
  const float* h2h  = (const float*)d_in[5];   // (64,256,256)
  const float* bias = (const float*)d_in[6];   // (64,256)

  float* out_states = (float*)d_out;                                        // (2049,64,2,256)
  float* out_fb     = out_states + (size_t)(T_STEPS+1) * N_MOD * 2 * N_HID; // (2048,64,256)

  // workspace: flags (64 x u32, stride 16B -> 1KB) | hy double-buffer (128KB)
  unsigned* flags = (unsigned*)d_ws;
  float*    hyb   = (float*)((char*)d_ws + 1024);
  hipMemsetAsync(d_ws, 0, 1024, stream);       // flags start at 0 each call

  xpre_kernel<<<dim3(T_STEPS/64, N_MOD), dim3(256), 0, stream>>>(x, x2h, out_fb);

  void* args[] = {
    (void*)&init, (void*)&wmw, (void*)&conn, (void*)&h2h, (void*)&bias,
    (void*)&out_states, (void*)&out_fb, (void*)&hyb, (void*)&flags
  };
  hipLaunchCooperativeKernel((void*)archnet_step, dim3(64), dim3(512),
                             args, 0, stream);
}